// Round 3
// baseline (478.846 us; speedup 1.0000x reference)
//
#include <hip/hip_runtime.h>
#include <hip/hip_bf16.h>

// EncoderLayer on MI355X (gfx950).
// Pipeline: cast/transpose -> QKV GEMM (V written transposed in epilogue) ->
//           flash attn (QBLK=32/wave) -> proj GEMM (+bc +resid) -> LN1 ->
//           FFN1 GEMM (+b1, relu) -> FFN2 GEMM (+b2 +resid) -> LN2.

#define DEV __device__ __forceinline__

using s16x8 = __attribute__((ext_vector_type(8))) short;   // 8 bf16 (4 VGPR) MFMA frag
using f32x4 = __attribute__((ext_vector_type(4))) float;

DEV unsigned short f2bf(float f) {            // f32 -> bf16 RNE
  unsigned u = __float_as_uint(f);
  u += 0x7fffu + ((u >> 16) & 1u);
  return (unsigned short)(u >> 16);
}
DEV unsigned pack2bf(float a, float b) {
  return (unsigned)f2bf(a) | ((unsigned)f2bf(b) << 16);
}
DEV unsigned cvt_pk_bf16(float lo, float hi) {   // 1 VALU op
  unsigned r;
  asm("v_cvt_pk_bf16_f32 %0, %1, %2" : "=v"(r) : "v"(lo), "v"(hi));
  return r;
}
DEV f32x4 vmax4(f32x4 a, f32x4 b) {
  f32x4 r;
  r[0] = fmaxf(a[0], b[0]); r[1] = fmaxf(a[1], b[1]);
  r[2] = fmaxf(a[2], b[2]); r[3] = fmaxf(a[3], b[3]);
  return r;
}

typedef __attribute__((address_space(3))) unsigned lds_u32_t;
typedef const __attribute__((address_space(1))) unsigned glb_u32_t;

// async global->LDS, 16B per lane; lds dst is wave-uniform base (HW adds lane*16)
DEV void gld_lds16(const void* g, void* l) {
  __builtin_amdgcn_global_load_lds((glb_u32_t*)g, (lds_u32_t*)l, 16, 0, 0);
}

// ---------------------------------------------------------------------------
// GEMM: C[M][N] = A[M][K] * Bt[N][K]^T  (both bf16 row-major), fp32 acc.
// 128x128 tile, BK=32, 4 waves (2x2), each wave 64x64 = 4x4 16x16x32 frags.
// VOUT=1: cols >= 2048 are the V projection -> written TRANSPOSED to vtout
// as [(b*16+h)*64+d][token] (packed ushort4 over 4 consecutive tokens).
// ---------------------------------------------------------------------------
template<int RELU, int RESID, int OUTF, int VOUT>
__global__ __launch_bounds__(256)
void gemm_bt(const unsigned short* __restrict__ A, const unsigned short* __restrict__ Bt,
             unsigned short* __restrict__ Cb, float* __restrict__ Cf,
             const float* __restrict__ bias, const float* __restrict__ resid,
             unsigned short* __restrict__ vtout,
             int M, int N, int K)
{
  __shared__ unsigned short As[128 * 32];
  __shared__ unsigned short Bs[128 * 32];
  const int tid  = threadIdx.x;
  const int wave = tid >> 6, lane = tid & 63;
  const int g = lane >> 4, q = lane & 15;

  const int nwg  = gridDim.x * gridDim.y;
  const int flat = blockIdx.y * gridDim.x + blockIdx.x;
  const int rm   = (nwg & 7) ? flat : ((flat & 7) * (nwg >> 3) + (flat >> 3));
  const int m0 = (rm / gridDim.x) * 128, n0 = (rm % gridDim.x) * 128;
  const int wr = wave >> 1, wc = wave & 1;

  f32x4 acc[4][4] = {};

  const int i0 = wave * 512 + lane * 8;        // pass 0 element index in 128x32 tile
  const int i1 = 2048 + i0;                    // pass 1

  for (int kt = 0; kt < K; kt += 32) {
    gld_lds16(A  + (size_t)(m0 + (i0 >> 5)) * K + kt + (i0 & 31), As + wave * 512);
    gld_lds16(Bt + (size_t)(n0 + (i0 >> 5)) * K + kt + (i0 & 31), Bs + wave * 512);
    gld_lds16(A  + (size_t)(m0 + (i1 >> 5)) * K + kt + (i1 & 31), As + 2048 + wave * 512);
    gld_lds16(Bt + (size_t)(n0 + (i1 >> 5)) * K + kt + (i1 & 31), Bs + 2048 + wave * 512);
    __syncthreads();                            // drains vmcnt for global_load_lds
    s16x8 a[4], b[4];
#pragma unroll
    for (int m = 0; m < 4; ++m)
      a[m] = *(const s16x8*)(As + (wr * 64 + m * 16 + q) * 32 + g * 8);
#pragma unroll
    for (int n = 0; n < 4; ++n)
      b[n] = *(const s16x8*)(Bs + (wc * 64 + n * 16 + q) * 32 + g * 8);
#pragma unroll
    for (int m = 0; m < 4; ++m)
#pragma unroll
      for (int n = 0; n < 4; ++n)
        acc[m][n] = __builtin_amdgcn_mfma_f32_16x16x32_bf16(a[m], b[n], acc[m][n], 0, 0, 0);
    __syncthreads();
  }

  // epilogue: C/D layout col = lane&15, row = (lane>>4)*4 + reg
#pragma unroll
  for (int n = 0; n < 4; ++n) {
    const int col = n0 + wc * 64 + n * 16 + q;
    if (VOUT && col >= 2048) {                 // V projection: write transposed
      const int cv = col - 2048;
#pragma unroll
      for (int m = 0; m < 4; ++m) {
        const int row0 = m0 + wr * 64 + m * 16 + g * 4;
        const int bb = row0 >> 11;             // batch (uniform per block)
        ushort4 pk;
        pk.x = f2bf(acc[m][n][0]); pk.y = f2bf(acc[m][n][1]);
        pk.z = f2bf(acc[m][n][2]); pk.w = f2bf(acc[m][n][3]);
        *(ushort4*)(vtout + ((size_t)bb * 1024 + cv) * 2048 + (row0 & 2047)) = pk;
      }
    } else {
      const float bv = bias ? bias[col] : 0.0f;
#pragma unroll
      for (int m = 0; m < 4; ++m) {
        const int row0 = m0 + wr * 64 + m * 16 + g * 4;
#pragma unroll
        for (int r = 0; r < 4; ++r) {
          float v = acc[m][n][r] + bv;
          if (RELU) v = fmaxf(v, 0.0f);
          if (RESID) v += resid[(size_t)(row0 + r) * N + col];
          if (OUTF) Cf[(size_t)(row0 + r) * N + col] = v;
          else      Cb[(size_t)(row0 + r) * N + col] = f2bf(v);
        }
      }
    }
  }
}

// ---------------------------------------------------------------------------
// Flash attention, LDS-staged, QBLK=32 per wave (two 16-row halves).
// grid (16 q-tiles, 64 bh) -> XCD-chunk remapped. 4 waves/block = 128 q rows.
// K/V tiles [64][64] bf16 in LDS (shared by all 4 waves), double-buffered.
// Chunk-XOR swizzle on the GLOBAL SOURCE side (linear LDS dest) + on ds_read.
// S^T = mfma(K, Q): lane holds query q (col). O^T = mfma(V^T, P^T).
// Defer-max (THR=8) skips the O-rescale on no-growth tiles; exp2-domain p.
// ---------------------------------------------------------------------------
__global__ __launch_bounds__(256, 3)
void attn_kernel(const unsigned short* __restrict__ qkv,   // [8192][3072] Q|K|(dead V)
                 const unsigned short* __restrict__ vt,    // [(b*16+h)*64+d][2048]
                 const float* __restrict__ mask,           // [4][2048][2048]
                 unsigned short* __restrict__ outb)        // [8192][1024]
{
  __shared__ unsigned short Ks[2][4096];                   // [64 kv][64 d] swizzled
  __shared__ unsigned short Vs[2][4096];                   // [64 d][64 kv] swizzled
  __shared__ unsigned short Pl[4][2048];                   // per-wave P [32 q][64 kv]
  const int tid = threadIdx.x, wave = tid >> 6, lane = tid & 63;
  const int g = lane >> 4, q = lane & 15;

  // XCD-chunked remap: 1024 blocks -> 8 XCDs x 128; each XCD owns 8 bh values.
  const int flat = blockIdx.y * 16 + blockIdx.x;
  const int rm   = (flat & 7) * 128 + (flat >> 3);
  const int qt = rm & 15, bh = rm >> 4;
  const int b = bh >> 4, h = bh & 15;
  const int qrow = qt * 128 + wave * 32;
  const size_t tok0 = (size_t)b * 2048;

  s16x8 bq[2][2];                                          // [qb][kb] Q B-frags
#pragma unroll
  for (int qb = 0; qb < 2; ++qb) {
    const unsigned short* Qp = qkv + (tok0 + qrow + qb * 16 + q) * 3072 + h * 64;
    bq[qb][0] = *(const s16x8*)(Qp + g * 8);
    bq[qb][1] = *(const s16x8*)(Qp + 32 + g * 8);
  }
  const float* Mp0 = mask + ((size_t)b * 2048 + qrow + q) * 2048;
  const float* Mp1 = Mp0 + 16 * 2048;

  // staging source addresses (per-lane, pre-swizzled chunk)
  const int lr = lane >> 3;                 // row within 8-row group
  const int sc = (lane & 7) ^ lr;           // swizzled chunk index
  const unsigned short* Kg = qkv + tok0 * 3072 + 1024 + h * 64
                           + (size_t)(wave * 16 + lr) * 3072 + sc * 8;
  const unsigned short* Vg = vt + ((size_t)bh * 64 + wave * 16 + lr) * 2048 + sc * 8;
  unsigned short* KsW = Ks[0] + wave * 1024;
  unsigned short* VsW = Vs[0] + wave * 1024;

  auto STAGE = [&](int buf, int t) {
    const size_t ko = (size_t)t * (64 * 3072);
    const int    vo = t * 64;
    gld_lds16(Kg + ko,            KsW + buf * 4096);
    gld_lds16(Kg + ko + 8 * 3072, KsW + buf * 4096 + 512);
    gld_lds16(Vg + vo,            VsW + buf * 4096);
    gld_lds16(Vg + vo + 8 * 2048, VsW + buf * 4096 + 512);
  };

  f32x4 ot[2][4] = {};                       // [qb][m] O^T acc
  float mrun0 = -3.0e38f, mrun1 = -3.0e38f;
  float mnl0 = 0.0f, mnl1 = 0.0f;            // mrun * log2(e)
  float lsum0 = 0.0f, lsum1 = 0.0f;
  char* Pw = (char*)&Pl[wave][0];
  const float SC  = 0.125f;
  const float L2E = 1.4426950408889634f;

  STAGE(0, 0);
  __syncthreads();                           // tile 0 staged

  int cur = 0;
#pragma unroll 1
  for (int t = 0; t < 32; ++t) {
    if (t < 31) STAGE(cur ^ 1, t + 1);       // async; in flight across this iter
    f32x4 mk0[4], mk1[4];                    // mask for current tile (used ~300cy later)
#pragma unroll
    for (int m2 = 0; m2 < 4; ++m2) {
      mk0[m2] = *(const f32x4*)(Mp0 + t * 64 + m2 * 16 + g * 4);
      mk1[m2] = *(const f32x4*)(Mp1 + t * 64 + m2 * 16 + g * 4);
    }
    const unsigned short* Kt = Ks[cur];
    const unsigned short* Vt = Vs[cur];

    // QK^T: K A-frags shared by both q-halves -> 8 ds_read, 16 MFMA
    f32x4 st0[4] = {}, st1[4] = {};
    __builtin_amdgcn_s_setprio(1);
#pragma unroll
    for (int m2 = 0; m2 < 4; ++m2) {
      const unsigned short* kp = Kt + (m2 * 16 + q) * 64;
      const s16x8 ak0 = *(const s16x8*)(kp + ((g       ^ (q & 7)) * 8));
      const s16x8 ak1 = *(const s16x8*)(kp + (((g + 4) ^ (q & 7)) * 8));
      st0[m2] = __builtin_amdgcn_mfma_f32_16x16x32_bf16(ak0, bq[0][0], st0[m2], 0, 0, 0);
      st1[m2] = __builtin_amdgcn_mfma_f32_16x16x32_bf16(ak0, bq[1][0], st1[m2], 0, 0, 0);
      st0[m2] = __builtin_amdgcn_mfma_f32_16x16x32_bf16(ak1, bq[0][1], st0[m2], 0, 0, 0);
      st1[m2] = __builtin_amdgcn_mfma_f32_16x16x32_bf16(ak1, bq[1][1], st1[m2], 0, 0, 0);
    }
    __builtin_amdgcn_s_setprio(0);

    // scale + mask (two independent chains)
#pragma unroll
    for (int m2 = 0; m2 < 4; ++m2) {
#pragma unroll
      for (int r = 0; r < 4; ++r) {
        st0[m2][r] = fmaf(st0[m2][r], SC, mk0[m2][r]);
        st1[m2][r] = fmaf(st1[m2][r], SC, mk1[m2][r]);
      }
    }
    // balanced max trees + cross-g reduce
    f32x4 a0 = vmax4(vmax4(st0[0], st0[1]), vmax4(st0[2], st0[3]));
    f32x4 a1 = vmax4(vmax4(st1[0], st1[1]), vmax4(st1[2], st1[3]));
    float t0 = fmaxf(fmaxf(a0[0], a0[1]), fmaxf(a0[2], a0[3]));
    float t1 = fmaxf(fmaxf(a1[0], a1[1]), fmaxf(a1[2], a1[3]));
    t0 = fmaxf(t0, __shfl_xor(t0, 16));
    t0 = fmaxf(t0, __shfl_xor(t0, 32));
    t1 = fmaxf(t1, __shfl_xor(t1, 16));
    t1 = fmaxf(t1, __shfl_xor(t1, 32));

    // defer-max: rescale only when a row max grew by > 8 (P bounded by e^8)
    if (!__all(t0 <= mrun0 + 8.0f && t1 <= mrun1 + 8.0f)) {
      const float mn0 = fmaxf(mrun0, t0), mn1 = fmaxf(mrun1, t1);
      const float al0 = exp2f((mrun0 - mn0) * L2E);
      const float al1 = exp2f((mrun1 - mn1) * L2E);
      mrun0 = mn0; mrun1 = mn1;
      mnl0 = mn0 * L2E; mnl1 = mn1 * L2E;
      lsum0 *= al0; lsum1 *= al1;
#pragma unroll
      for (int m = 0; m < 4; ++m)
#pragma unroll
        for (int r = 0; r < 4; ++r) { ot[0][m][r] *= al0; ot[1][m][r] *= al1; }
    }

    // p = exp2(s*log2e - mnl); row sums; pack bf16 into P LDS (swizzled)
    float rs0 = 0.0f, rs1 = 0.0f;
#pragma unroll
    for (int m2 = 0; m2 < 4; ++m2) {
#pragma unroll
      for (int r = 0; r < 4; ++r) {
        st0[m2][r] = exp2f(fmaf(st0[m2][r], L2E, -mnl0));
        st1[m2][r] = exp2f(fmaf(st1[m2][r], L2E, -mnl1));
      }
      rs0 += (st0[m2][0] + st0[m2][1]) + (st0[m2][2] + st0[m2][3]);
      rs1 += (st1[m2][0] + st1[m2][1]) + (st1[m2][2] + st1[m2][3]);
      const int bir = m2 * 32 + g * 8;
      const int ca  = (((bir >> 4) ^ (q & 7)) << 4) + (bir & 15);
      uint2 pk0, pk1;
      pk0.x = cvt_pk_bf16(st0[m2][0], st0[m2][1]);
      pk0.y = cvt_pk_bf16(st0[m2][2], st0[m2][3]);
      pk1.x = cvt_pk_bf16(st1[m2][0], st1[m2][1]);
      pk1.y = cvt_pk_bf16(st1[m2][2], st1[m2][3]);
      *(uint2*)(Pw + q * 128 + ca)        = pk0;   // same-wave DS FIFO: no barrier
      *(uint2*)(Pw + (16 + q) * 128 + ca) = pk1;
    }
    rs0 += __shfl_xor(rs0, 16); rs0 += __shfl_xor(rs0, 32);
    rs1 += __shfl_xor(rs1, 16); rs1 += __shfl_xor(rs1, 32);
    lsum0 += rs0; lsum1 += rs1;

    // PV: V A-frags shared by both q-halves -> 12 ds_read, 16 MFMA
    __builtin_amdgcn_s_setprio(1);
#pragma unroll
    for (int kb = 0; kb < 2; ++kb) {
      const int blk = (kb * 4 + g) ^ (q & 7);
      const s16x8 pb0 = *(const s16x8*)(Pw + q * 128 + blk * 16);
      const s16x8 pb1 = *(const s16x8*)(Pw + (16 + q) * 128 + blk * 16);
#pragma unroll
      for (int m = 0; m < 4; ++m) {
        const s16x8 av = *(const s16x8*)(Vt + (m * 16 + q) * 64 + blk * 8);
        ot[0][m] = __builtin_amdgcn_mfma_f32_16x16x32_bf16(av, pb0, ot[0][m], 0, 0, 0);
        ot[1][m] = __builtin_amdgcn_mfma_f32_16x16x32_bf16(av, pb1, ot[1][m], 0, 0, 0);
      }
    }
    __builtin_amdgcn_s_setprio(0);

    __syncthreads();                         // drains vmcnt: next tile staged; guards dbuf
    cur ^= 1;
  }

  // finalize: O[q][d] = ot/lsum; transpose through LDS for coalesced 16B stores
  const float inv0 = 1.0f / lsum0, inv1 = 1.0f / lsum1;
#pragma unroll
  for (int m = 0; m < 4; ++m) {
    const int bir = m * 32 + g * 8;
    const int ca  = (((bir >> 4) ^ (q & 7)) << 4) + (bir & 15);
    uint2 pk0, pk1;
    pk0.x = cvt_pk_bf16(ot[0][m][0] * inv0, ot[0][m][1] * inv0);
    pk0.y = cvt_pk_bf16(ot[0][m][2] * inv0, ot[0][m][3] * inv0);
    pk1.x = cvt_pk_bf16(ot[1][m][0] * inv1, ot[1][m][1] * inv1);
    pk1.y = cvt_pk_bf16(ot[1][m][2] * inv1, ot[1][m][3] * inv1);
    *(uint2*)(Pw + q * 128 + ca)        = pk0;
    *(uint2*)(Pw + (16 + q) * 128 + ca) = pk1;
  }
#pragma unroll
  for (int p = 0; p < 4; ++p) {
    const int c  = p * 64 + lane;            // 0..255 over [32 q][8 chunks]
    const int qq = c >> 3, cc = c & 7;
    const int blk = cc ^ (qq & 7);
    const s16x8 vv = *(const s16x8*)(Pw + qq * 128 + blk * 16);
    *(s16x8*)(outb + (tok0 + qrow + qq) * 1024 + h * 64 + cc * 8) = vv;
  }
}

// ---------------------------------------------------------------------------
// Row LayerNorm over D=1024. One 256-thread block per row. In-place safe.
// ---------------------------------------------------------------------------
__global__ __launch_bounds__(256)
void ln_kernel(const float* __restrict__ in, float* __restrict__ outf,
               unsigned short* __restrict__ outb,
               const float* __restrict__ gam, const float* __restrict__ bet)
{
  __shared__ float red[8];
  const int row = blockIdx.x, tid = threadIdx.x;
  const f32x4 v = *(const f32x4*)(in + (size_t)row * 1024 + tid * 4);
  float s  = v[0] + v[1] + v[2] + v[3];
  float ss = v[0]*v[0] + v[1]*v[1] + v[2]*v[2] + v[3]*v[3];
#pragma unroll
  for (int o = 1; o < 64; o <<= 1) { s += __shfl_xor(s, o); ss += __shfl_xor(ss, o); }
  if ((tid & 63) == 0) { red[tid >> 6] = s; red[4 + (tid >> 6)] = ss; }
  __syncthreads();
  s  = red[0] + red[1] + red[2] + red[3];
  ss = red[4] + red[5] + red[6] + red[7];
  const float mean = s * (1.0f / 1024.0f);
  const float var  = ss * (1.0f / 1024.0f) - mean * mean;
  const float rstd = rsqrtf(var + 1e-5f);
  const f32x4 gm = *(const f32x4*)(gam + tid * 4);
  const f32x4 bt = *(const f32x4*)(bet + tid * 4);
  f32x4 o;
#pragma unroll
  for (int j = 0; j < 4; ++j) o[j] = (v[j] - mean) * rstd * gm[j] + bt[j];
  if (outf) *(f32x4*)(outf + (size_t)row * 1024 + tid * 4) = o;
  if (outb) {
    uint2 pk; pk.x = pack2bf(o[0], o[1]); pk.y = pack2bf(o[2], o[3]);
    *(uint2*)(outb + (size_t)row * 1024 + tid * 4) = pk;
  }
}

// f32 [R][C] -> bf16 [C][R]
__global__ __launch_bounds__(256)
void tcast_kernel(const float* __restrict__ in, unsigned short* __restrict__ out, int R, int C)
{
  __shared__ float t[32][33];
  const int tx = threadIdx.x & 31, ty = threadIdx.x >> 5;
  const int c0 = blockIdx.x * 32, r0 = blockIdx.y * 32;
#pragma unroll
  for (int k = 0; k < 4; ++k)
    t[ty + k * 8][tx] = in[(size_t)(r0 + ty + k * 8) * C + c0 + tx];
  __syncthreads();
#pragma unroll
  for (int k = 0; k < 4; ++k)
    out[(size_t)(c0 + ty + k * 8) * R + r0 + tx] = f2bf(t[tx][ty + k * 8]);
}

__global__ __launch_bounds__(256)
void cast_x_kernel(const float* __restrict__ in, unsigned short* __restrict__ out)
{
  const size_t i = ((size_t)blockIdx.x * 256 + threadIdx.x) * 4;
  const f32x4 v = *(const f32x4*)(in + i);
  uint2 pk; pk.x = pack2bf(v[0], v[1]); pk.y = pack2bf(v[2], v[3]);
  *(uint2*)(out + i) = pk;
}

extern "C" void kernel_launch(void* const* d_in, const int* in_sizes, int n_in,
                              void* d_out, int out_size, void* d_ws, size_t ws_size,
                              hipStream_t stream)
{
  (void)in_sizes; (void)n_in; (void)out_size; (void)ws_size;  // needs ws_size >= 160MB
  const float* x   = (const float*)d_in[0];
  const float* msk = (const float*)d_in[1];
  const float* Wq  = (const float*)d_in[2];
  const float* Wk  = (const float*)d_in[3];
  const float* Wv  = (const float*)d_in[4];
  const float* Wc  = (const float*)d_in[5];
  const float* bc  = (const float*)d_in[6];
  const float* W1  = (const float*)d_in[7];
  const float* b1  = (const float*)d_in[8];
  const float* W2  = (const float*)d_in[9];
  const float* b2  = (const float*)d_in[10];
  const float* g1  = (const float*)d_in[11];
  const float* be1 = (const float*)d_in[12];
  const float* g2  = (const float*)d_in[13];
  const float* be2 = (const float*)d_in[14];
  float* out = (float*)d_out;
  char* ws = (char*)d_ws;
  const size_t MB = 1u << 20;
  unsigned short* xb    = (unsigned short*)(ws + 0 * MB);
  unsigned short* wqkvt = (unsigned short*)(ws + 16 * MB);
  unsigned short* wct   = (unsigned short*)(ws + 22 * MB);
  unsigned short* w1t   = (unsigned short*)(ws + 24 * MB);
  unsigned short* w2t   = (unsigned short*)(ws + 28 * MB);
  unsigned short* qkv   = (unsigned short*)(ws + 32 * MB);
  unsigned short* vt    = (unsigned short*)(ws + 80 * MB);
  unsigned short* attnb = xb;                        // reuse after QKV GEMM
  float*          y1    = (float*)(ws + 32 * MB);    // over dead qkv
  unsigned short* h1b   = (unsigned short*)(ws + 64 * MB);
  float*          h1f   = (float*)(ws + 96 * MB);
  unsigned short* midb  = (unsigned short*)(ws + 128 * MB);

  cast_x_kernel<<<8192, 256, 0, stream>>>(x, xb);
  tcast_kernel<<<dim3(32, 32), 256, 0, stream>>>(Wq, wqkvt,               1024, 1024);
  tcast_kernel<<<dim3(32, 32), 256, 0, stream>>>(Wk, wqkvt + 1024 * 1024, 1024, 1024);
  tcast_kernel<<<dim3(32, 32), 256, 0, stream>>>(Wv, wqkvt + 2048 * 1024, 1024, 1024);
  tcast_kernel<<<dim3(32, 32), 256, 0, stream>>>(Wc, wct,                 1024, 1024);
  tcast_kernel<<<dim3(64, 32), 256, 0, stream>>>(W1, w1t,                 1024, 2048);
  tcast_kernel<<<dim3(32, 64), 256, 0, stream>>>(W2, w2t,                 2048, 1024);

  // QKV GEMM; V columns land transposed in vt (tv_kernel eliminated)
  gemm_bt<0, 0, 0, 1><<<dim3(24, 64), 256, 0, stream>>>(xb, wqkvt, qkv, nullptr,
                                                        nullptr, nullptr, vt, 8192, 3072, 1024);
  attn_kernel<<<dim3(16, 64), 256, 0, stream>>>(qkv, vt, msk, attnb);
  gemm_bt<0, 1, 1, 0><<<dim3(8, 64), 256, 0, stream>>>(attnb, wct, nullptr, y1,
                                                       bc, x, nullptr, 8192, 1024, 1024);
  ln_kernel<<<8192, 256, 0, stream>>>(y1, h1f, h1b, g1, be1);
  gemm_bt<1, 0, 0, 0><<<dim3(16, 64), 256, 0, stream>>>(h1b, w1t, midb, nullptr,
                                                        b1, nullptr, nullptr, 8192, 2048, 1024);
  gemm_bt<0, 1, 1, 0><<<dim3(8, 64), 256, 0, stream>>>(midb, w2t, nullptr, out,
                                                       b2, h1f, nullptr, 8192, 1024, 2048);
  ln_kernel<<<8192, 256, 0, stream>>>(out, out, nullptr, g2, be2);
}

// Round 4
// 453.711 us; speedup vs baseline: 1.0554x; 1.0554x over previous
//
#include <hip/hip_runtime.h>
#include <hip/hip_bf16.h>

// EncoderLayer on MI355X (gfx950).
// cast/transpose -> QKV GEMM (8-phase 256², V transposed in epilogue) ->
// flash attn (16 q-rows/wave) -> proj GEMM (128²,+bc+resid) -> LN1 ->
// FFN1 GEMM (8-phase 256²,+b1,relu) -> FFN2 GEMM (128²,+b2+resid) -> LN2.

#define DEV __device__ __forceinline__

using s16x8 = __attribute__((ext_vector_type(8))) short;   // 8 bf16 MFMA frag
using f32x4 = __attribute__((ext_vector_type(4))) float;

DEV unsigned short f2bf(float f) {            // f32 -> bf16 RNE
  unsigned u = __float_as_uint(f);
  u += 0x7fffu + ((u >> 16) & 1u);
  return (unsigned short)(u >> 16);
}
DEV unsigned pack2bf(float a, float b) {
  return (unsigned)f2bf(a) | ((unsigned)f2bf(b) << 16);
}
DEV unsigned cvt_pk_bf16(float lo, float hi) {
  unsigned r;
  asm("v_cvt_pk_bf16_f32 %0, %1, %2" : "=v"(r) : "v"(lo), "v"(hi));
  return r;
}
DEV f32x4 vmax4(f32x4 a, f32x4 b) {
  f32x4 r;
  r[0] = fmaxf(a[0], b[0]); r[1] = fmaxf(a[1], b[1]);
  r[2] = fmaxf(a[2], b[2]); r[3] = fmaxf(a[3], b[3]);
  return r;
}

typedef __attribute__((address_space(3))) unsigned lds_u32_t;
typedef const __attribute__((address_space(1))) unsigned glb_u32_t;

DEV void gld_lds16(const void* g, void* l) {
  __builtin_amdgcn_global_load_lds((glb_u32_t*)g, (lds_u32_t*)l, 16, 0, 0);
}

// ---------------------------------------------------------------------------
// 8-phase 256x256 GEMM (T2+T3+T4+T5): C[M][N] = A[M][K] * Bt[N][K]^T, bf16 out.
// 512 thr = 8 waves (2M x 4N), per-wave 128x64. BK=64, LDS 128KB dbuf.
// Per K-tile: 4 phases {stage 1 half-tile of kt+1 (2 gld_lds), ds_read quadrant
// frags, setprio(1) MFMA x16 setprio(0), raw s_barrier}. vmcnt(2) at K-tile
// head only (counted: 2 youngest = this phase's own issues). Chunk-XOR swizzle
// (chunk ^= row&7 on 16B units): inverse-applied on global source (linear LDS
// dest, rule #21), applied on ds_read -> conflict-free b128.
// ---------------------------------------------------------------------------
template<int RELU, int VOUT>
__global__ __launch_bounds__(512, 2)
void gemm8p(const unsigned short* __restrict__ A, const unsigned short* __restrict__ Bt,
            unsigned short* __restrict__ Cb, const float* __restrict__ bias,
            unsigned short* __restrict__ vtout, int M, int N, int K)
{
  __shared__ unsigned short Sh[2][2][256 * 64];       // [buf][A|B][row][k] 128KB
  const int tid = threadIdx.x;
  const int w = tid >> 6, lane = tid & 63;
  const int g = lane >> 4, q = lane & 15;
  const int wr = w >> 2, wc = w & 3;

  const int nwg  = gridDim.x * gridDim.y;
  const int flat = blockIdx.y * gridDim.x + blockIdx.x;
  const int rm   = (flat & 7) * (nwg >> 3) + (flat >> 3);   // XCD-chunked (nwg%8==0)
  const int m0 = (rm / gridDim.x) * 256, n0 = (rm % gridDim.x) * 256;

  f32x4 acc[8][4] = {};

  // staging: wave w instr j covers rows j*64 + w*8 + (lane>>3); LDS linear,
  // source column chunk pre-swizzled by row&7 = lane>>3.
  const int srow = w * 8 + (lane >> 3);
  const int scol = ((lane & 7) ^ (lane >> 3)) * 8;
  const unsigned short* Ag = A  + (size_t)(m0 + srow) * K + scol;
  const unsigned short* Bg = Bt + (size_t)(n0 + srow) * K + scol;

  auto STG = [&](const unsigned short* Gb, int buf, int ab, int half, int kt) {
    const unsigned short* gs = Gb + (size_t)(half * 128) * K + kt * 64;
    unsigned short* ls = &Sh[buf][ab][(half * 128 + w * 8) * 64];
    gld_lds16(gs, ls);
    gld_lds16(gs + (size_t)64 * K, ls + 64 * 64);
  };
  auto LDA = [&](int buf, int mq, s16x8 af[4][2]) {
#pragma unroll
    for (int mm = 0; mm < 4; ++mm) {
      const unsigned short* rp = &Sh[buf][0][(wr * 128 + mq * 64 + mm * 16 + q) * 64];
#pragma unroll
      for (int kk = 0; kk < 2; ++kk)
        af[mm][kk] = *(const s16x8*)(rp + (((kk * 4 + g) ^ (q & 7)) * 8));
    }
  };
  auto LDB = [&](int buf, int nq, s16x8 bf[2][2]) {
#pragma unroll
    for (int nn = 0; nn < 2; ++nn) {
      const unsigned short* rp = &Sh[buf][1][(wc * 64 + nq * 32 + nn * 16 + q) * 64];
#pragma unroll
      for (int kk = 0; kk < 2; ++kk)
        bf[nn][kk] = *(const s16x8*)(rp + (((kk * 4 + g) ^ (q & 7)) * 8));
    }
  };
  auto MQ = [&](int mq, int nq, const s16x8 af[4][2], const s16x8 bf[2][2]) {
    __builtin_amdgcn_s_setprio(1);
#pragma unroll
    for (int kk = 0; kk < 2; ++kk)
#pragma unroll
      for (int mm = 0; mm < 4; ++mm)
#pragma unroll
        for (int nn = 0; nn < 2; ++nn)
          acc[mq * 4 + mm][nq * 2 + nn] = __builtin_amdgcn_mfma_f32_16x16x32_bf16(
              af[mm][kk], bf[nn][kk], acc[mq * 4 + mm][nq * 2 + nn], 0, 0, 0);
    __builtin_amdgcn_s_setprio(0);
  };
  auto BAR = [&]() { __builtin_amdgcn_sched_barrier(0); __builtin_amdgcn_s_barrier(); };

  // prologue: stage K-tile 0 fully into buf0 (8 gld_lds/wave-pair pattern)
  STG(Ag, 0, 0, 0, 0); STG(Ag, 0, 0, 1, 0);
  STG(Bg, 0, 1, 0, 0); STG(Bg, 0, 1, 1, 0);

  const int NKT = K >> 6;
  s16x8 af[4][2], bf0[2][2], bf1[2][2];
#pragma unroll 1
  for (int kt = 0; kt < NKT; ++kt) {
    const int b = kt & 1, sb = b ^ 1, kn = kt + 1;
    const bool stg = (kn < NKT);
    // phase 1: stage A_lo(kt+1); counted wait for kt's 8 loads; quadrant (0,0)
    if (stg) { STG(Ag, sb, 0, 0, kn); asm volatile("s_waitcnt vmcnt(2)" ::: "memory"); }
    else     {                        asm volatile("s_waitcnt vmcnt(0)" ::: "memory"); }
    BAR();
    LDA(b, 0, af); LDB(b, 0, bf0);
    MQ(0, 0, af, bf0);
    BAR();
    // phase 2: stage A_hi(kt+1); quadrant (0,1)
    if (stg) STG(Ag, sb, 0, 1, kn);
    LDB(b, 1, bf1);
    MQ(0, 1, af, bf1);
    BAR();
    // phase 3: stage B_lo(kt+1); quadrant (1,0)
    if (stg) STG(Bg, sb, 1, 0, kn);
    LDA(b, 1, af);
    MQ(1, 0, af, bf0);
    BAR();
    // phase 4: stage B_hi(kt+1); quadrant (1,1)
    if (stg) STG(Bg, sb, 1, 1, kn);
    MQ(1, 1, af, bf1);
    BAR();
  }

  // epilogue: C/D layout col = lane&15, row = (lane>>4)*4 + reg
#pragma unroll
  for (int n = 0; n < 4; ++n) {
    const int col = n0 + wc * 64 + n * 16 + q;
    if (VOUT && col >= 2048) {                 // V projection: write transposed
      const int cv = col - 2048;
#pragma unroll
      for (int m = 0; m < 8; ++m) {
        const int row0 = m0 + wr * 128 + m * 16 + g * 4;
        const int bb = row0 >> 11;
        ushort4 pk;
        pk.x = f2bf(acc[m][n][0]); pk.y = f2bf(acc[m][n][1]);
        pk.z = f2bf(acc[m][n][2]); pk.w = f2bf(acc[m][n][3]);
        *(ushort4*)(vtout + ((size_t)bb * 1024 + cv) * 2048 + (row0 & 2047)) = pk;
      }
    } else {
      const float bv = bias ? bias[col] : 0.0f;
#pragma unroll
      for (int m = 0; m < 8; ++m) {
        const int row0 = m0 + wr * 128 + m * 16 + g * 4;
#pragma unroll
        for (int r = 0; r < 4; ++r) {
          float v = acc[m][n][r] + bv;
          if (RELU) v = fmaxf(v, 0.0f);
          Cb[(size_t)(row0 + r) * N + col] = f2bf(v);
        }
      }
    }
  }
}

// ---------------------------------------------------------------------------
// 128x128 GEMM (proven m97-style), used for N=1024 GEMMs (proj, FFN2) where
// 256² tiles would leave half the CUs idle. f32 out + residual supported.
// ---------------------------------------------------------------------------
template<int RELU, int RESID, int OUTF>
__global__ __launch_bounds__(256)
void gemm_bt(const unsigned short* __restrict__ A, const unsigned short* __restrict__ Bt,
             unsigned short* __restrict__ Cb, float* __restrict__ Cf,
             const float* __restrict__ bias, const float* __restrict__ resid,
             int M, int N, int K)
{
  __shared__ unsigned short As[128 * 32];
  __shared__ unsigned short Bs[128 * 32];
  const int tid  = threadIdx.x;
  const int wave = tid >> 6, lane = tid & 63;
  const int g = lane >> 4, q = lane & 15;

  const int nwg  = gridDim.x * gridDim.y;
  const int flat = blockIdx.y * gridDim.x + blockIdx.x;
  const int rm   = (nwg & 7) ? flat : ((flat & 7) * (nwg >> 3) + (flat >> 3));
  const int m0 = (rm / gridDim.x) * 128, n0 = (rm % gridDim.x) * 128;
  const int wr = wave >> 1, wc = wave & 1;

  f32x4 acc[4][4] = {};

  const int i0 = wave * 512 + lane * 8;
  const int i1 = 2048 + i0;

  for (int kt = 0; kt < K; kt += 32) {
    gld_lds16(A  + (size_t)(m0 + (i0 >> 5)) * K + kt + (i0 & 31), As + wave * 512);
    gld_lds16(Bt + (size_t)(n0 + (i0 >> 5)) * K + kt + (i0 & 31), Bs + wave * 512);
    gld_lds16(A  + (size_t)(m0 + (i1 >> 5)) * K + kt + (i1 & 31), As + 2048 + wave * 512);
    gld_lds16(Bt + (size_t)(n0 + (i1 >> 5)) * K + kt + (i1 & 31), Bs + 2048 + wave * 512);
    __syncthreads();
    s16x8 a[4], b[4];
#pragma unroll
    for (int m = 0; m < 4; ++m)
      a[m] = *(const s16x8*)(As + (wr * 64 + m * 16 + q) * 32 + g * 8);
#pragma unroll
    for (int n = 0; n < 4; ++n)
      b[n] = *(const s16x8*)(Bs + (wc * 64 + n * 16 + q) * 32 + g * 8);
#pragma unroll
    for (int m = 0; m < 4; ++m)
#pragma unroll
      for (int n = 0; n < 4; ++n)
        acc[m][n] = __builtin_amdgcn_mfma_f32_16x16x32_bf16(a[m], b[n], acc[m][n], 0, 0, 0);
    __syncthreads();
  }

#pragma unroll
  for (int n = 0; n < 4; ++n) {
    const int col = n0 + wc * 64 + n * 16 + q;
    const float bv = bias ? bias[col] : 0.0f;
#pragma unroll
    for (int m = 0; m < 4; ++m) {
      const int row0 = m0 + wr * 64 + m * 16 + g * 4;
#pragma unroll
      for (int r = 0; r < 4; ++r) {
        float v = acc[m][n][r] + bv;
        if (RELU) v = fmaxf(v, 0.0f);
        if (RESID) v += resid[(size_t)(row0 + r) * N + col];
        if (OUTF) Cf[(size_t)(row0 + r) * N + col] = v;
        else      Cb[(size_t)(row0 + r) * N + col] = f2bf(v);
      }
    }
  }
}

// ---------------------------------------------------------------------------
// Flash attention (R1 geometry: 16 q-rows/wave, 2048 blocks) + exp2-domain
// softmax + defer-max (THR=8). K/V tiles [64][64] LDS, double-buffered via
// global_load_lds; chunk-XOR swizzle source-side. S^T = mfma(K,Q);
// O^T = mfma(V^T,P^T) with P through per-wave swizzled LDS.
// ---------------------------------------------------------------------------
__global__ __launch_bounds__(256, 4)
void attn_kernel(const unsigned short* __restrict__ qkv,   // [8192][3072] Q|K|(dead V)
                 const unsigned short* __restrict__ vt,    // [(b*16+h)*64+d][2048]
                 const float* __restrict__ mask,           // [4][2048][2048]
                 unsigned short* __restrict__ outb)        // [8192][1024]
{
  __shared__ unsigned short Ks[2][4096];
  __shared__ unsigned short Vs[2][4096];
  __shared__ unsigned short Pl[4][1024];
  const int tid = threadIdx.x, wave = tid >> 6, lane = tid & 63;
  const int g = lane >> 4, q = lane & 15;

  const int flat = blockIdx.y * 32 + blockIdx.x;
  const int rm   = (flat & 7) * 256 + (flat >> 3);
  const int qt = rm & 31, bh = rm >> 5;
  const int b = bh >> 4, h = bh & 15;
  const int qrow = qt * 64 + wave * 16;
  const size_t tok0 = (size_t)b * 2048;

  const unsigned short* Qp = qkv + (tok0 + qrow + q) * 3072 + h * 64;
  const s16x8 bq0 = *(const s16x8*)(Qp + g * 8);
  const s16x8 bq1 = *(const s16x8*)(Qp + 32 + g * 8);
  const float* Mp = mask + ((size_t)b * 2048 + qrow + q) * 2048;

  const int lr = lane >> 3;
  const int sc = (lane & 7) ^ lr;
  const unsigned short* Kg = qkv + tok0 * 3072 + 1024 + h * 64
                           + (size_t)(wave * 16 + lr) * 3072 + sc * 8;
  const unsigned short* Vg = vt + ((size_t)bh * 64 + wave * 16 + lr) * 2048 + sc * 8;
  unsigned short* KsW = Ks[0] + wave * 1024;
  unsigned short* VsW = Vs[0] + wave * 1024;

  auto STAGE = [&](int buf, int t) {
    const size_t ko = (size_t)t * (64 * 3072);
    const int    vo = t * 64;
    gld_lds16(Kg + ko,            KsW + buf * 4096);
    gld_lds16(Kg + ko + 8 * 3072, KsW + buf * 4096 + 512);
    gld_lds16(Vg + vo,            VsW + buf * 4096);
    gld_lds16(Vg + vo + 8 * 2048, VsW + buf * 4096 + 512);
  };

  f32x4 ot[4] = {};
  f32x4 mkc[4], mkn[4];
  float mrun = -3.0e38f, mnl = 0.0f, lsum = 0.0f;
  char* Pw = (char*)&Pl[wave][0];
  const float SC  = 0.125f;
  const float L2E = 1.4426950408889634f;

  STAGE(0, 0);
#pragma unroll
  for (int m2 = 0; m2 < 4; ++m2) mkc[m2] = *(const f32x4*)(Mp + m2 * 16 + g * 4);
  __syncthreads();

  int cur = 0;
#pragma unroll 1
  for (int t = 0; t < 32; ++t) {
    if (t < 31) {
      STAGE(cur ^ 1, t + 1);
#pragma unroll
      for (int m2 = 0; m2 < 4; ++m2)
        mkn[m2] = *(const f32x4*)(Mp + (t + 1) * 64 + m2 * 16 + g * 4);
    }
    const unsigned short* Kt = Ks[cur];
    const unsigned short* Vt = Vs[cur];

    f32x4 st[4] = {};
    __builtin_amdgcn_s_setprio(1);
#pragma unroll
    for (int m2 = 0; m2 < 4; ++m2) {
      const unsigned short* kp = Kt + (m2 * 16 + q) * 64;
      const s16x8 ak0 = *(const s16x8*)(kp + ((g       ^ (q & 7)) * 8));
      const s16x8 ak1 = *(const s16x8*)(kp + (((g + 4) ^ (q & 7)) * 8));
      st[m2] = __builtin_amdgcn_mfma_f32_16x16x32_bf16(ak0, bq0, st[m2], 0, 0, 0);
      st[m2] = __builtin_amdgcn_mfma_f32_16x16x32_bf16(ak1, bq1, st[m2], 0, 0, 0);
    }
    __builtin_amdgcn_s_setprio(0);

#pragma unroll
    for (int m2 = 0; m2 < 4; ++m2)
#pragma unroll
      for (int r = 0; r < 4; ++r)
        st[m2][r] = fmaf(st[m2][r], SC, mkc[m2][r]);

    f32x4 a0 = vmax4(vmax4(st[0], st[1]), vmax4(st[2], st[3]));
    float tmax = fmaxf(fmaxf(a0[0], a0[1]), fmaxf(a0[2], a0[3]));
    tmax = fmaxf(tmax, __shfl_xor(tmax, 16));
    tmax = fmaxf(tmax, __shfl_xor(tmax, 32));

    // defer-max (T13): rescale only when a row max grew past THR=8
    if (!__all(tmax <= mrun + 8.0f)) {
      const float mn = fmaxf(mrun, tmax);
      const float al = exp2f((mrun - mn) * L2E);
      mrun = mn; mnl = mn * L2E;
      lsum *= al;
#pragma unroll
      for (int m = 0; m < 4; ++m) {
        ot[m][0] *= al; ot[m][1] *= al; ot[m][2] *= al; ot[m][3] *= al;
      }
    }

    float rsum = 0.0f;
#pragma unroll
    for (int m2 = 0; m2 < 4; ++m2) {
#pragma unroll
      for (int r = 0; r < 4; ++r)
        st[m2][r] = exp2f(fmaf(st[m2][r], L2E, -mnl));
      rsum += (st[m2][0] + st[m2][1]) + (st[m2][2] + st[m2][3]);
      const int bir  = m2 * 32 + g * 8;
      const int addr = q * 128 + (((bir >> 4) ^ (q & 7)) << 4) + (bir & 15);
      uint2 pk;
      pk.x = cvt_pk_bf16(st[m2][0], st[m2][1]);
      pk.y = cvt_pk_bf16(st[m2][2], st[m2][3]);
      *(uint2*)(Pw + addr) = pk;               // same-wave DS FIFO: no barrier
    }
    rsum += __shfl_xor(rsum, 16);
    rsum += __shfl_xor(rsum, 32);
    lsum += rsum;

    __builtin_amdgcn_s_setprio(1);
#pragma unroll
    for (int kb = 0; kb < 2; ++kb) {
      const int blk = (kb * 4 + g) ^ (q & 7);
      const s16x8 pb = *(const s16x8*)(Pw + q * 128 + blk * 16);
#pragma unroll
      for (int m = 0; m < 4; ++m) {
        const s16x8 av = *(const s16x8*)(Vt + (m * 16 + q) * 64 + blk * 8);
        ot[m] = __builtin_amdgcn_mfma_f32_16x16x32_bf16(av, pb, ot[m], 0, 0, 0);
      }
    }
    __builtin_amdgcn_s_setprio(0);

#pragma unroll
    for (int m2 = 0; m2 < 4; ++m2) mkc[m2] = mkn[m2];
    __syncthreads();                           // drains vmcnt: next tile staged
    cur ^= 1;
  }

  const float inv = 1.0f / lsum;
#pragma unroll
  for (int m = 0; m < 4; ++m) {
    const int bir  = m * 32 + g * 8;
    const int addr = q * 128 + (((bir >> 4) ^ (q & 7)) << 4) + (bir & 15);
    uint2 pk;
    pk.x = cvt_pk_bf16(ot[m][0] * inv, ot[m][1] * inv);
    pk.y = cvt_pk_bf16(ot[m][2] * inv, ot[m][3] * inv);
    *(uint2*)(Pw + addr) = pk;
  }
#pragma unroll
  for (int p = 0; p < 2; ++p) {
    const int c  = p * 64 + lane;
    const int qq = c >> 3, cc = c & 7;
    const int blk = cc ^ (qq & 7);
    const s16x8 vv = *(const s16x8*)(Pw + qq * 128 + blk * 16);
    *(s16x8*)(outb + (tok0 + qrow + qq) * 1024 + h * 64 + cc * 8) = vv;
  }
}

// ---------------------------------------------------------------------------
// Row LayerNorm over D=1024.
// ---------------------------------------------------------------------------
__global__ __launch_bounds__(256)
void ln_kernel(const float* __restrict__ in, float* __restrict__ outf,
               unsigned short* __restrict__ outb,
               const float* __restrict__ gam, const float* __restrict__ bet)
{
  __shared__ float red[8];
  const int row = blockIdx.x, tid = threadIdx.x;
  const f32x4 v = *(const f32x4*)(in + (size_t)row * 1024 + tid * 4);
  float s  = v[0] + v[1] + v[2] + v[3];
  float ss = v[0]*v[0] + v[1]*v[1] + v[2]*v[2] + v[3]*v[3];
#pragma unroll
  for (int o = 1; o < 64; o <<= 1) { s += __shfl_xor(s, o); ss += __shfl_xor(ss, o); }
  if ((tid & 63) == 0) { red[tid >> 6] = s; red[4 + (tid >> 6)] = ss; }
  __syncthreads();
  s  = red[0] + red[1] + red[2] + red[3];
  ss = red[4] + red[5] + red[6] + red[7];
  const float mean = s * (1.0f / 1024.0f);
  const float var  = ss * (1.0f / 1024.0f) - mean * mean;
  const float rstd = rsqrtf(var + 1e-5f);
  const f32x4 gm = *(const f32x4*)(gam + tid * 4);
  const f32x4 bt = *(const f32x4*)(bet + tid * 4);
  f32x4 o;
#pragma unroll
  for (int j = 0; j < 4; ++j) o[j] = (v[j] - mean) * rstd * gm[j] + bt[j];
  if (outf) *(f32x4*)(outf + (size_t)row * 1024 + tid * 4) = o;
  if (outb) {
    uint2 pk; pk.x = pack2bf(o[0], o[1]); pk.y = pack2bf(o[2], o[3]);
    *(uint2*)(outb + (size_t)row * 1024 + tid * 4) = pk;
  }
}

// f32 [R][C] -> bf16 [C][R]
__global__ __launch_bounds__(256)
void tcast_kernel(const float* __restrict__ in, unsigned short* __restrict__ out, int R, int C)
{
  __shared__ float t[32][33];
  const int tx = threadIdx.x & 31, ty = threadIdx.x >> 5;
  const int c0 = blockIdx.x * 32, r0 = blockIdx.y * 32;
#pragma unroll
  for (int k = 0; k < 4; ++k)
    t[ty + k * 8][tx] = in[(size_t)(r0 + ty + k * 8) * C + c0 + tx];
  __syncthreads();
#pragma unroll
  for (int k = 0; k < 4; ++k)
    out[(size_t)(c0 + ty + k * 8) * R + r0 + tx] = f2bf(t[tx][ty + k * 8]);
}

__global__ __launch_bounds__(256)
void cast_x_kernel(const float* __restrict__ in, unsigned short* __restrict__ out)
{
  const size_t i = ((size_t)blockIdx.x * 256 + threadIdx.x) * 4;
  const f32x4 v = *(const f32x4*)(in + i);
  uint2 pk; pk.x = pack2bf(v[0], v[1]); pk.y = pack2bf(v[2], v[3]);
  *(uint2*)(out + i) = pk;
}

extern "C" void kernel_launch(void* const* d_in, const int* in_sizes, int n_in,
                              void* d_out, int out_size, void* d_ws, size_t ws_size,
                              hipStream_t stream)
{
  (void)in_sizes; (void)n_in; (void)out_size; (void)ws_size;  // needs ws_size >= 160MB
  const float* x   = (const float*)d_in[0];
  const float* msk = (const float*)d_in[1];
  const float* Wq  = (const float*)d_in[2];
  const float* Wk  = (const float*)d_in[3];
  const float* Wv  = (const float*)d_in[4];
  const float* Wc  = (const float*)d_in[5];
  const float* bc  = (const float*)d_in[6];
  const float* W1  = (const float*)d_in[7];
  const float* b1  = (const float*)d_in[8];
  const float* W2  = (const float*)d_in[9];
  const float* b2  = (const float*)d_in[10];
  const float* g1  = (const float*)d_in[11];
  const float* be1 = (const float*)d_in[12];
  const float* g2  = (const float*)d_in[13];
  const float* be2 = (const float*)d_in[14];
  float* out = (float*)d_out;
  char* ws = (char*)d_ws;
  const size_t MB = 1u << 20;
  unsigned short* xb    = (unsigned short*)(ws + 0 * MB);
  unsigned short* wqkvt = (unsigned short*)(ws + 16 * MB);
  unsigned short* wct   = (unsigned short*)(ws + 22 * MB);
  unsigned short* w1t   = (unsigned short*)(ws + 24 * MB);
  unsigned short* w2t   = (unsigned short*)(ws + 28 * MB);
  unsigned short* qkv   = (unsigned short*)(ws + 32 * MB);
  unsigned short* vt    = (unsigned short*)(ws + 80 * MB);
  unsigned short* attnb = xb;
  float*          y1    = (float*)(ws + 32 * MB);
  unsigned short* h1b   = (unsigned short*)(ws + 64 * MB);
  float*          h1f   = (float*)(ws + 96 * MB);
  unsigned short* midb  = (unsigned short*)(ws + 128 * MB);

  cast_x_kernel<<<8192, 256, 0, stream>>>(x, xb);
  tcast_kernel<<<dim3(32, 32), 256, 0, stream>>>(Wq, wqkvt,               1024, 1024);
  tcast_kernel<<<dim3(32, 32), 256, 0, stream>>>(Wk, wqkvt + 1024 * 1024, 1024, 1024);
  tcast_kernel<<<dim3(32, 32), 256, 0, stream>>>(Wv, wqkvt + 2048 * 1024, 1024, 1024);
  tcast_kernel<<<dim3(32, 32), 256, 0, stream>>>(Wc, wct,                 1024, 1024);
  tcast_kernel<<<dim3(64, 32), 256, 0, stream>>>(W1, w1t,                 1024, 2048);
  tcast_kernel<<<dim3(32, 64), 256, 0, stream>>>(W2, w2t,                 2048, 1024);

  // QKV GEMM (8-phase 256²); V columns land transposed in vt
  gemm8p<0, 1><<<dim3(12, 32), 512, 0, stream>>>(xb, wqkvt, qkv, nullptr, vt,
                                                 8192, 3072, 1024);
  attn_kernel<<<dim3(32, 64), 256, 0, stream>>>(qkv, vt, msk, attnb);
  gemm_bt<0, 1, 1><<<dim3(8, 64), 256, 0, stream>>>(attnb, wct, nullptr, y1,
                                                    bc, x, 8192, 1024, 1024);
  ln_kernel<<<8192, 256, 0, stream>>>(y1, h1f, h1b, g1, be1);
  // FFN1 (8-phase 256², +b1, relu)
  gemm8p<1, 0><<<dim3(8, 32), 512, 0, stream>>>(h1b, w1t, midb, b1, nullptr,
                                                8192, 2048, 1024);
  gemm_bt<0, 1, 1><<<dim3(8, 64), 256, 0, stream>>>(midb, w2t, nullptr, out,
                                                    b2, h1f, 8192, 1024, 2048);
  ln_kernel<<<8192, 256, 0, stream>>>(out, out, nullptr, g2, be2);
}

// Round 5
// 432.111 us; speedup vs baseline: 1.1082x; 1.0500x over previous
//
#include <hip/hip_runtime.h>
#include <hip/hip_bf16.h>

// EncoderLayer on MI355X (gfx950).
// cast/transpose -> QKV GEMM (8-phase 256², V transposed, Q pre-scaled by
// 0.125*log2e) -> flash attn (log2-domain softmax, MFMA row-sum) ->
// proj GEMM (+bc, bf16 resid xb, bf16 out) -> LN1 (bf16 in/out) ->
// FFN1 GEMM (8-phase, +b1, relu) -> FFN2 GEMM (+b2, bf16 resid h1b) -> LN2.

#define DEV __device__ __forceinline__

using s16x8 = __attribute__((ext_vector_type(8))) short;   // 8 bf16 MFMA frag
using f32x4 = __attribute__((ext_vector_type(4))) float;

DEV unsigned short f2bf(float f) {            // f32 -> bf16 RNE
  unsigned u = __float_as_uint(f);
  u += 0x7fffu + ((u >> 16) & 1u);
  return (unsigned short)(u >> 16);
}
DEV unsigned cvt_pk_bf16(float lo, float hi) {
  unsigned r;
  asm("v_cvt_pk_bf16_f32 %0, %1, %2" : "=v"(r) : "v"(lo), "v"(hi));
  return r;
}
DEV float bf2f(unsigned short b) { return __uint_as_float((unsigned)b << 16); }

typedef __attribute__((address_space(3))) unsigned lds_u32_t;
typedef const __attribute__((address_space(1))) unsigned glb_u32_t;

DEV void gld_lds16(const void* g, void* l) {
  __builtin_amdgcn_global_load_lds((glb_u32_t*)g, (lds_u32_t*)l, 16, 0, 0);
}

// ---------------------------------------------------------------------------
// 8-phase 256x256 GEMM (T2+T3+T4+T5). 512 thr = 8 waves (2Mx4N), BK=64,
// 128KB LDS dbuf, counted vmcnt at K-tile head only, chunk-XOR swizzle.
// VOUT=1 (QKV): cols<1024 are Q -> scaled by 0.125*log2e; cols>=2048 are V ->
// written transposed to vtout [(b*16+h)*64+d][token].
// ---------------------------------------------------------------------------
template<int RELU, int VOUT>
__global__ __launch_bounds__(512, 2)
void gemm8p(const unsigned short* __restrict__ A, const unsigned short* __restrict__ Bt,
            unsigned short* __restrict__ Cb, const float* __restrict__ bias,
            unsigned short* __restrict__ vtout, int M, int N, int K)
{
  __shared__ unsigned short Sh[2][2][256 * 64];
  const int tid = threadIdx.x;
  const int w = tid >> 6, lane = tid & 63;
  const int g = lane >> 4, q = lane & 15;
  const int wr = w >> 2, wc = w & 3;

  const int nwg  = gridDim.x * gridDim.y;
  const int flat = blockIdx.y * gridDim.x + blockIdx.x;
  const int rm   = (flat & 7) * (nwg >> 3) + (flat >> 3);
  const int m0 = (rm / gridDim.x) * 256, n0 = (rm % gridDim.x) * 256;

  f32x4 acc[8][4] = {};

  const int srow = w * 8 + (lane >> 3);
  const int scol = ((lane & 7) ^ (lane >> 3)) * 8;
  const unsigned short* Ag = A  + (size_t)(m0 + srow) * K + scol;
  const unsigned short* Bg = Bt + (size_t)(n0 + srow) * K + scol;

  auto STG = [&](const unsigned short* Gb, int buf, int ab, int half, int kt) {
    const unsigned short* gs = Gb + (size_t)(half * 128) * K + kt * 64;
    unsigned short* ls = &Sh[buf][ab][(half * 128 + w * 8) * 64];
    gld_lds16(gs, ls);
    gld_lds16(gs + (size_t)64 * K, ls + 64 * 64);
  };
  auto LDA = [&](int buf, int mq, s16x8 af[4][2]) {
#pragma unroll
    for (int mm = 0; mm < 4; ++mm) {
      const unsigned short* rp = &Sh[buf][0][(wr * 128 + mq * 64 + mm * 16 + q) * 64];
#pragma unroll
      for (int kk = 0; kk < 2; ++kk)
        af[mm][kk] = *(const s16x8*)(rp + (((kk * 4 + g) ^ (q & 7)) * 8));
    }
  };
  auto LDB = [&](int buf, int nq, s16x8 bf[2][2]) {
#pragma unroll
    for (int nn = 0; nn < 2; ++nn) {
      const unsigned short* rp = &Sh[buf][1][(wc * 64 + nq * 32 + nn * 16 + q) * 64];
#pragma unroll
      for (int kk = 0; kk < 2; ++kk)
        bf[nn][kk] = *(const s16x8*)(rp + (((kk * 4 + g) ^ (q & 7)) * 8));
    }
  };
  auto MQ = [&](int mq, int nq, const s16x8 af[4][2], const s16x8 bf[2][2]) {
    __builtin_amdgcn_s_setprio(1);
#pragma unroll
    for (int kk = 0; kk < 2; ++kk)
#pragma unroll
      for (int mm = 0; mm < 4; ++mm)
#pragma unroll
        for (int nn = 0; nn < 2; ++nn)
          acc[mq * 4 + mm][nq * 2 + nn] = __builtin_amdgcn_mfma_f32_16x16x32_bf16(
              af[mm][kk], bf[nn][kk], acc[mq * 4 + mm][nq * 2 + nn], 0, 0, 0);
    __builtin_amdgcn_s_setprio(0);
  };
  auto BAR = [&]() { __builtin_amdgcn_sched_barrier(0); __builtin_amdgcn_s_barrier(); };

  STG(Ag, 0, 0, 0, 0); STG(Ag, 0, 0, 1, 0);
  STG(Bg, 0, 1, 0, 0); STG(Bg, 0, 1, 1, 0);

  const int NKT = K >> 6;
  s16x8 af[4][2], bf0[2][2], bf1[2][2];
#pragma unroll 1
  for (int kt = 0; kt < NKT; ++kt) {
    const int b = kt & 1, sb = b ^ 1, kn = kt + 1;
    const bool stg = (kn < NKT);
    if (stg) { STG(Ag, sb, 0, 0, kn); asm volatile("s_waitcnt vmcnt(2)" ::: "memory"); }
    else     {                        asm volatile("s_waitcnt vmcnt(0)" ::: "memory"); }
    BAR();
    LDA(b, 0, af); LDB(b, 0, bf0);
    MQ(0, 0, af, bf0);
    BAR();
    if (stg) STG(Ag, sb, 0, 1, kn);
    LDB(b, 1, bf1);
    MQ(0, 1, af, bf1);
    BAR();
    if (stg) STG(Bg, sb, 1, 0, kn);
    LDA(b, 1, af);
    MQ(1, 0, af, bf0);
    BAR();
    if (stg) STG(Bg, sb, 1, 1, kn);
    MQ(1, 1, af, bf1);
    BAR();
  }

#pragma unroll
  for (int n = 0; n < 4; ++n) {
    const int col = n0 + wc * 64 + n * 16 + q;
    if (VOUT && col >= 2048) {                 // V: write transposed
      const int cv = col - 2048;
#pragma unroll
      for (int m = 0; m < 8; ++m) {
        const int row0 = m0 + wr * 128 + m * 16 + g * 4;
        const int bb = row0 >> 11;
        ushort4 pk;
        pk.x = f2bf(acc[m][n][0]); pk.y = f2bf(acc[m][n][1]);
        pk.z = f2bf(acc[m][n][2]); pk.w = f2bf(acc[m][n][3]);
        *(ushort4*)(vtout + ((size_t)bb * 1024 + cv) * 2048 + (row0 & 2047)) = pk;
      }
    } else {
      // Q columns pre-scaled so QK^T lands in exp2 domain
      const float scl = (VOUT && col < 1024) ? 0.18033688011112042f : 1.0f;
      const float bv = bias ? bias[col] : 0.0f;
#pragma unroll
      for (int m = 0; m < 8; ++m) {
        const int row0 = m0 + wr * 128 + m * 16 + g * 4;
#pragma unroll
        for (int r = 0; r < 4; ++r) {
          float v = acc[m][n][r] * scl + bv;
          if (RELU) v = fmaxf(v, 0.0f);
          Cb[(size_t)(row0 + r) * N + col] = f2bf(v);
        }
      }
    }
  }
}

// ---------------------------------------------------------------------------
// 128x128 GEMM (m97-style) for N=1024 GEMMs. RESID: 0 none, 1 f32, 2 bf16.
// OUTF: 1 f32 out, 0 bf16 out.
// ---------------------------------------------------------------------------
template<int RELU, int RESID, int OUTF>
__global__ __launch_bounds__(256)
void gemm_bt(const unsigned short* __restrict__ A, const unsigned short* __restrict__ Bt,
             unsigned short* __restrict__ Cb, float* __restrict__ Cf,
             const float* __restrict__ bias, const float* __restrict__ resid,
             const unsigned short* __restrict__ residb,
             int M, int N, int K)
{
  __shared__ unsigned short As[128 * 32];
  __shared__ unsigned short Bs[128 * 32];
  const int tid  = threadIdx.x;
  const int wave = tid >> 6, lane = tid & 63;
  const int g = lane >> 4, q = lane & 15;

  const int nwg  = gridDim.x * gridDim.y;
  const int flat = blockIdx.y * gridDim.x + blockIdx.x;
  const int rm   = (nwg & 7) ? flat : ((flat & 7) * (nwg >> 3) + (flat >> 3));
  const int m0 = (rm / gridDim.x) * 128, n0 = (rm % gridDim.x) * 128;
  const int wr = wave >> 1, wc = wave & 1;

  f32x4 acc[4][4] = {};

  const int i0 = wave * 512 + lane * 8;
  const int i1 = 2048 + i0;

  for (int kt = 0; kt < K; kt += 32) {
    gld_lds16(A  + (size_t)(m0 + (i0 >> 5)) * K + kt + (i0 & 31), As + wave * 512);
    gld_lds16(Bt + (size_t)(n0 + (i0 >> 5)) * K + kt + (i0 & 31), Bs + wave * 512);
    gld_lds16(A  + (size_t)(m0 + (i1 >> 5)) * K + kt + (i1 & 31), As + 2048 + wave * 512);
    gld_lds16(Bt + (size_t)(n0 + (i1 >> 5)) * K + kt + (i1 & 31), Bs + 2048 + wave * 512);
    __syncthreads();
    s16x8 a[4], b[4];
#pragma unroll
    for (int m = 0; m < 4; ++m)
      a[m] = *(const s16x8*)(As + (wr * 64 + m * 16 + q) * 32 + g * 8);
#pragma unroll
    for (int n = 0; n < 4; ++n)
      b[n] = *(const s16x8*)(Bs + (wc * 64 + n * 16 + q) * 32 + g * 8);
#pragma unroll
    for (int m = 0; m < 4; ++m)
#pragma unroll
      for (int n = 0; n < 4; ++n)
        acc[m][n] = __builtin_amdgcn_mfma_f32_16x16x32_bf16(a[m], b[n], acc[m][n], 0, 0, 0);
    __syncthreads();
  }

#pragma unroll
  for (int n = 0; n < 4; ++n) {
    const int col = n0 + wc * 64 + n * 16 + q;
    const float bv = bias ? bias[col] : 0.0f;
#pragma unroll
    for (int m = 0; m < 4; ++m) {
      const int row0 = m0 + wr * 64 + m * 16 + g * 4;
#pragma unroll
      for (int r = 0; r < 4; ++r) {
        float v = acc[m][n][r] + bv;
        if (RELU) v = fmaxf(v, 0.0f);
        if (RESID == 1) v += resid[(size_t)(row0 + r) * N + col];
        if (RESID == 2) v += bf2f(residb[(size_t)(row0 + r) * N + col]);
        if (OUTF) Cf[(size_t)(row0 + r) * N + col] = v;
        else      Cb[(size_t)(row0 + r) * N + col] = f2bf(v);
      }
    }
  }
}

// ---------------------------------------------------------------------------
// Flash attention. 16 q-rows/wave, 2048 blocks. Q pre-scaled by 0.125*log2e
// so S arrives in exp2 domain. Softmax denominator via ones-MFMA (sacc[0]).
// Defer-max THR = 8*log2e. K/V LDS-staged dbuf, chunk-XOR swizzle.
// ---------------------------------------------------------------------------
__global__ __launch_bounds__(256, 4)
void attn_kernel(const unsigned short* __restrict__ qkv,   // [8192][3072]
                 const unsigned short* __restrict__ vt,    // [(b*16+h)*64+d][2048]
                 const float* __restrict__ mask,           // [4][2048][2048]
                 unsigned short* __restrict__ outb)        // [8192][1024]
{
  __shared__ unsigned short Ks[2][4096];
  __shared__ unsigned short Vs[2][4096];
  __shared__ unsigned short Pl[4][1024];
  const int tid = threadIdx.x, wave = tid >> 6, lane = tid & 63;
  const int g = lane >> 4, q = lane & 15;

  const int flat = blockIdx.y * 32 + blockIdx.x;
  const int rm   = (flat & 7) * 256 + (flat >> 3);
  const int qt = rm & 31, bh = rm >> 5;
  const int b = bh >> 4, h = bh & 15;
  const int qrow = qt * 64 + wave * 16;
  const size_t tok0 = (size_t)b * 2048;

  const unsigned short* Qp = qkv + (tok0 + qrow + q) * 3072 + h * 64;
  const s16x8 bq0 = *(const s16x8*)(Qp + g * 8);
  const s16x8 bq1 = *(const s16x8*)(Qp + 32 + g * 8);
  const float* Mp = mask + ((size_t)b * 2048 + qrow + q) * 2048;

  const int lr = lane >> 3;
  const int sc = (lane & 7) ^ lr;
  const unsigned short* Kg = qkv + tok0 * 3072 + 1024 + h * 64
                           + (size_t)(wave * 16 + lr) * 3072 + sc * 8;
  const unsigned short* Vg = vt + ((size_t)bh * 64 + wave * 16 + lr) * 2048 + sc * 8;
  unsigned short* KsW = Ks[0] + wave * 1024;
  unsigned short* VsW = Vs[0] + wave * 1024;

  auto STAGE = [&](int buf, int t) {
    const size_t ko = (size_t)t * (64 * 3072);
    const int    vo = t * 64;
    gld_lds16(Kg + ko,            KsW + buf * 4096);
    gld_lds16(Kg + ko + 8 * 3072, KsW + buf * 4096 + 512);
    gld_lds16(Vg + vo,            VsW + buf * 4096);
    gld_lds16(Vg + vo + 8 * 2048, VsW + buf * 4096 + 512);
  };

  s16x8 ones;
#pragma unroll
  for (int j = 0; j < 8; ++j) ones[j] = (short)0x3F80;     // bf16 1.0

  f32x4 ot[4] = {};
  f32x4 sacc = {};                           // [0] = running softmax denominator
  f32x4 mkc[4], mkn[4];
  float m = -3.0e38f;                        // running max, log2 domain
  char* Pw = (char*)&Pl[wave][0];
  const float L2E = 1.4426950408889634f;
  const float THR = 11.541560327111707f;     // 8*log2(e)

  STAGE(0, 0);
#pragma unroll
  for (int m2 = 0; m2 < 4; ++m2) mkc[m2] = *(const f32x4*)(Mp + m2 * 16 + g * 4);
  __syncthreads();

  int cur = 0;
#pragma unroll 1
  for (int t = 0; t < 32; ++t) {
    if (t < 31) {
      STAGE(cur ^ 1, t + 1);
#pragma unroll
      for (int m2 = 0; m2 < 4; ++m2)
        mkn[m2] = *(const f32x4*)(Mp + (t + 1) * 64 + m2 * 16 + g * 4);
    }
    const unsigned short* Kt = Ks[cur];
    const unsigned short* Vt = Vs[cur];

    f32x4 st[4] = {};
    __builtin_amdgcn_s_setprio(1);
#pragma unroll
    for (int m2 = 0; m2 < 4; ++m2) {
      const unsigned short* kp = Kt + (m2 * 16 + q) * 64;
      const s16x8 ak0 = *(const s16x8*)(kp + ((g       ^ (q & 7)) * 8));
      const s16x8 ak1 = *(const s16x8*)(kp + (((g + 4) ^ (q & 7)) * 8));
      st[m2] = __builtin_amdgcn_mfma_f32_16x16x32_bf16(ak0, bq0, st[m2], 0, 0, 0);
      st[m2] = __builtin_amdgcn_mfma_f32_16x16x32_bf16(ak1, bq1, st[m2], 0, 0, 0);
    }
    __builtin_amdgcn_s_setprio(0);

    // add mask*log2e (S already in log2 domain via pre-scaled Q)
#pragma unroll
    for (int m2 = 0; m2 < 4; ++m2)
#pragma unroll
      for (int r = 0; r < 4; ++r)
        st[m2][r] = fmaf(mkc[m2][r], L2E, st[m2][r]);

    // row max: max3-friendly chains per m2, then combine + cross-g shfl
    float c0 = fmaxf(fmaxf(fmaxf(st[0][0], st[0][1]), st[0][2]), st[0][3]);
    float c1 = fmaxf(fmaxf(fmaxf(st[1][0], st[1][1]), st[1][2]), st[1][3]);
    float c2 = fmaxf(fmaxf(fmaxf(st[2][0], st[2][1]), st[2][2]), st[2][3]);
    float c3 = fmaxf(fmaxf(fmaxf(st[3][0], st[3][1]), st[3][2]), st[3][3]);
    float tmax = fmaxf(fmaxf(fmaxf(c0, c1), c2), c3);
    tmax = fmaxf(tmax, __shfl_xor(tmax, 16));
    tmax = fmaxf(tmax, __shfl_xor(tmax, 32));

    // defer-max (T13)
    if (!__all(tmax <= m + THR)) {
      const float mn = fmaxf(m, tmax);
      const float al = exp2f(m - mn);
      m = mn;
      sacc[0] *= al;
#pragma unroll
      for (int mm = 0; mm < 4; ++mm) {
        ot[mm][0] *= al; ot[mm][1] *= al; ot[mm][2] *= al; ot[mm][3] *= al;
      }
    }

    // p = exp2(s - m); pack to LDS (swizzled). Denominator comes from MFMA.
#pragma unroll
    for (int m2 = 0; m2 < 4; ++m2) {
#pragma unroll
      for (int r = 0; r < 4; ++r)
        st[m2][r] = exp2f(st[m2][r] - m);
      const int bir  = m2 * 32 + g * 8;
      const int addr = q * 128 + (((bir >> 4) ^ (q & 7)) << 4) + (bir & 15);
      uint2 pk;
      pk.x = cvt_pk_bf16(st[m2][0], st[m2][1]);
      pk.y = cvt_pk_bf16(st[m2][2], st[m2][3]);
      *(uint2*)(Pw + addr) = pk;             // same-wave DS FIFO
    }

    __builtin_amdgcn_s_setprio(1);
#pragma unroll
    for (int kb = 0; kb < 2; ++kb) {
      const int blk = (kb * 4 + g) ^ (q & 7);
      const s16x8 pb = *(const s16x8*)(Pw + q * 128 + blk * 16);
      sacc = __builtin_amdgcn_mfma_f32_16x16x32_bf16(ones, pb, sacc, 0, 0, 0);
#pragma unroll
      for (int mm = 0; mm < 4; ++mm) {
        const s16x8 av = *(const s16x8*)(Vt + (mm * 16 + q) * 64 + blk * 8);
        ot[mm] = __builtin_amdgcn_mfma_f32_16x16x32_bf16(av, pb, ot[mm], 0, 0, 0);
      }
    }
    __builtin_amdgcn_s_setprio(0);

#pragma unroll
    for (int m2 = 0; m2 < 4; ++m2) mkc[m2] = mkn[m2];
    __syncthreads();
    cur ^= 1;
  }

  const float inv = 1.0f / sacc[0];
#pragma unroll
  for (int mm = 0; mm < 4; ++mm) {
    const int bir  = mm * 32 + g * 8;
    const int addr = q * 128 + (((bir >> 4) ^ (q & 7)) << 4) + (bir & 15);
    uint2 pk;
    pk.x = cvt_pk_bf16(ot[mm][0] * inv, ot[mm][1] * inv);
    pk.y = cvt_pk_bf16(ot[mm][2] * inv, ot[mm][3] * inv);
    *(uint2*)(Pw + addr) = pk;
  }
#pragma unroll
  for (int p = 0; p < 2; ++p) {
    const int c  = p * 64 + lane;
    const int qq = c >> 3, cc = c & 7;
    const int blk = cc ^ (qq & 7);
    const s16x8 vv = *(const s16x8*)(Pw + qq * 128 + blk * 16);
    *(s16x8*)(outb + (tok0 + qrow + qq) * 1024 + h * 64 + cc * 8) = vv;
  }
}

// ---------------------------------------------------------------------------
// Row LayerNorm over D=1024. INBF: input bf16 (else f32). Outputs optional.
// ---------------------------------------------------------------------------
template<int INBF>
__global__ __launch_bounds__(256)
void ln_kernel(const float* __restrict__ inf, const unsigned short* __restrict__ inb,
               float* __restrict__ outf, unsigned short* __restrict__ outb,
               const float* __restrict__ gam, const float* __restrict__ bet)
{
  __shared__ float red[8];
  const int row = blockIdx.x, tid = threadIdx.x;
  f32x4 v;
  if (INBF) {
    const uint2 u = *(const uint2*)(inb + (size_t)row * 1024 + tid * 4);
    v[0] = __uint_as_float(u.x << 16); v[1] = __uint_as_float(u.x & 0xffff0000u);
    v[2] = __uint_as_float(u.y << 16); v[3] = __uint_as_float(u.y & 0xffff0000u);
  } else {
    v = *(const f32x4*)(inf + (size_t)row * 1024 + tid * 4);
  }
  float s  = v[0] + v[1] + v[2] + v[3];
  float ss = v[0]*v[0] + v[1]*v[1] + v[2]*v[2] + v[3]*v[3];
#pragma unroll
  for (int o = 1; o < 64; o <<= 1) { s += __shfl_xor(s, o); ss += __shfl_xor(ss, o); }
  if ((tid & 63) == 0) { red[tid >> 6] = s; red[4 + (tid >> 6)] = ss; }
  __syncthreads();
  s  = red[0] + red[1] + red[2] + red[3];
  ss = red[4] + red[5] + red[6] + red[7];
  const float mean = s * (1.0f / 1024.0f);
  const float var  = ss * (1.0f / 1024.0f) - mean * mean;
  const float rstd = rsqrtf(var + 1e-5f);
  const f32x4 gm = *(const f32x4*)(gam + tid * 4);
  const f32x4 bt = *(const f32x4*)(bet + tid * 4);
  f32x4 o;
#pragma unroll
  for (int j = 0; j < 4; ++j) o[j] = (v[j] - mean) * rstd * gm[j] + bt[j];
  if (outf) *(f32x4*)(outf + (size_t)row * 1024 + tid * 4) = o;
  if (outb) {
    uint2 pk; pk.x = cvt_pk_bf16(o[0], o[1]); pk.y = cvt_pk_bf16(o[2], o[3]);
    *(uint2*)(outb + (size_t)row * 1024 + tid * 4) = pk;
  }
}

// f32 [R][C] -> bf16 [C][R]
__global__ __launch_bounds__(256)
void tcast_kernel(const float* __restrict__ in, unsigned short* __restrict__ out, int R, int C)
{
  __shared__ float t[32][33];
  const int tx = threadIdx.x & 31, ty = threadIdx.x >> 5;
  const int c0 = blockIdx.x * 32, r0 = blockIdx.y * 32;
#pragma unroll
  for (int k = 0; k < 4; ++k)
    t[ty + k * 8][tx] = in[(size_t)(r0 + ty + k * 8) * C + c0 + tx];
  __syncthreads();
#pragma unroll
  for (int k = 0; k < 4; ++k)
    out[(size_t)(c0 + ty + k * 8) * R + r0 + tx] = f2bf(t[tx][ty + k * 8]);
}

__global__ __launch_bounds__(256)
void cast_x_kernel(const float* __restrict__ in, unsigned short* __restrict__ out)
{
  const size_t i = ((size_t)blockIdx.x * 256 + threadIdx.x) * 4;
  const f32x4 v = *(const f32x4*)(in + i);
  uint2 pk; pk.x = cvt_pk_bf16(v[0], v[1]); pk.y = cvt_pk_bf16(v[2], v[3]);
  *(uint2*)(out + i) = pk;
}

extern "C" void kernel_launch(void* const* d_in, const int* in_sizes, int n_in,
                              void* d_out, int out_size, void* d_ws, size_t ws_size,
                              hipStream_t stream)
{
  (void)in_sizes; (void)n_in; (void)out_size; (void)ws_size;  // needs ws_size >= 144MB
  const float* x   = (const float*)d_in[0];
  const float* msk = (const float*)d_in[1];
  const float* Wq  = (const float*)d_in[2];
  const float* Wk  = (const float*)d_in[3];
  const float* Wv  = (const float*)d_in[4];
  const float* Wc  = (const float*)d_in[5];
  const float* bc  = (const float*)d_in[6];
  const float* W1  = (const float*)d_in[7];
  const float* b1  = (const float*)d_in[8];
  const float* W2  = (const float*)d_in[9];
  const float* b2  = (const float*)d_in[10];
  const float* g1  = (const float*)d_in[11];
  const float* be1 = (const float*)d_in[12];
  const float* g2  = (const float*)d_in[13];
  const float* be2 = (const float*)d_in[14];
  float* out = (float*)d_out;
  char* ws = (char*)d_ws;
  const size_t MB = 1u << 20;
  unsigned short* xb    = (unsigned short*)(ws + 0 * MB);    // bf16 x (also proj resid)
  unsigned short* wqkvt = (unsigned short*)(ws + 16 * MB);
  unsigned short* wct   = (unsigned short*)(ws + 22 * MB);
  unsigned short* w1t   = (unsigned short*)(ws + 24 * MB);
  unsigned short* w2t   = (unsigned short*)(ws + 28 * MB);
  unsigned short* qkv   = (unsigned short*)(ws + 32 * MB);   // 48MB, dead after attn
  unsigned short* vt    = (unsigned short*)(ws + 80 * MB);   // 16MB
  unsigned short* attnb = (unsigned short*)(ws + 96 * MB);   // 16MB
  unsigned short* y1b   = (unsigned short*)(ws + 112 * MB);  // 16MB
  unsigned short* midb  = (unsigned short*)(ws + 32 * MB);   // 32MB over dead qkv
  unsigned short* z2b   = (unsigned short*)(ws + 64 * MB);   // 16MB over dead qkv
  unsigned short* h1b   = (unsigned short*)(ws + 128 * MB);  // 16MB

  cast_x_kernel<<<8192, 256, 0, stream>>>(x, xb);
  tcast_kernel<<<dim3(32, 32), 256, 0, stream>>>(Wq, wqkvt,               1024, 1024);
  tcast_kernel<<<dim3(32, 32), 256, 0, stream>>>(Wk, wqkvt + 1024 * 1024, 1024, 1024);
  tcast_kernel<<<dim3(32, 32), 256, 0, stream>>>(Wv, wqkvt + 2048 * 1024, 1024, 1024);
  tcast_kernel<<<dim3(32, 32), 256, 0, stream>>>(Wc, wct,                 1024, 1024);
  tcast_kernel<<<dim3(64, 32), 256, 0, stream>>>(W1, w1t,                 1024, 2048);
  tcast_kernel<<<dim3(32, 64), 256, 0, stream>>>(W2, w2t,                 2048, 1024);

  gemm8p<0, 1><<<dim3(12, 32), 512, 0, stream>>>(xb, wqkvt, qkv, nullptr, vt,
                                                 8192, 3072, 1024);
  attn_kernel<<<dim3(32, 64), 256, 0, stream>>>(qkv, vt, msk, attnb);
  gemm_bt<0, 2, 0><<<dim3(8, 64), 256, 0, stream>>>(attnb, wct, y1b, nullptr,
                                                    bc, nullptr, xb, 8192, 1024, 1024);
  ln_kernel<1><<<8192, 256, 0, stream>>>(nullptr, y1b, nullptr, h1b, g1, be1);
  gemm8p<1, 0><<<dim3(8, 32), 512, 0, stream>>>(h1b, w1t, midb, b1, nullptr,
                                                8192, 2048, 1024);
  gemm_bt<0, 2, 0><<<dim3(8, 64), 256, 0, stream>>>(midb, w2t, z2b, nullptr,
                                                    b2, nullptr, h1b, 8192, 1024, 2048);
  ln_kernel<1><<<8192, 256, 0, stream>>>(nullptr, z2b, out, nullptr, g2, be2);
}